// Round 1
// baseline (2237.524 us; speedup 1.0000x reference)
//
#include <hip/hip_runtime.h>
#include <hip/hip_bf16.h>
#include <cstdint>
#include <cstddef>

typedef __bf16 bf16;
typedef __attribute__((ext_vector_type(4))) __bf16 bf16x4;
typedef __attribute__((ext_vector_type(8))) __bf16 bf16x8;
typedef __attribute__((ext_vector_type(4))) float f32x4;

#define NR 8192      // B*S rows
#define DIM_D 1024
#define DIM_H 4096

// ---------------------------------------------------------------- helpers

__device__ __forceinline__ void gload_lds16(const void* g, void* l) {
  __builtin_amdgcn_global_load_lds(
      (const __attribute__((address_space(1))) void*)g,
      (__attribute__((address_space(3))) void*)l, 16, 0, 0);
}

// Chebyshev T_k; kidx is block-uniform (no divergence).
__device__ __forceinline__ float cheb_eval(float x, int kidx) {
  if (kidx == 0) return 1.0f;
  if (kidx == 1) return x;
  const float x2 = x * x;
  if (kidx == 2) return 2.0f * x2 - 1.0f;
  if (kidx == 3) return x * (4.0f * x2 - 3.0f);
  return 8.0f * x2 * (x2 - 1.0f) + 1.0f;   // T4
}

// ---------------------------------------------------------------- prep kernels

// xt = tanh(x), fp32 -> bf16, 4 elems/thread
__global__ __launch_bounds__(256) void k_tanh_x(const float* __restrict__ x,
                                                bf16* __restrict__ xt) {
  const size_t i = ((size_t)blockIdx.x * 256 + threadIdx.x) * 4;
  const float4 v = *(const float4*)(x + i);
  bf16x4 r;
  r[0] = (bf16)tanhf(v.x);
  r[1] = (bf16)tanhf(v.y);
  r[2] = (bf16)tanhf(v.z);
  r[3] = (bf16)tanhf(v.w);
  *(bf16x4*)(xt + i) = r;
}

// Bt[o][k*IN + i] = coef[i][o][k]  (coef layout [IN][OUT][5] fp32)
// one block per output row o; writes are lane-contiguous, reads L3-absorbed.
__global__ __launch_bounds__(256) void k_prep_w(const float* __restrict__ coef,
                                                bf16* __restrict__ Bt,
                                                const int IN, const int OUT) {
  const int o = blockIdx.x;
  const size_t base = (size_t)o * IN * 5;
  for (int i = threadIdx.x; i < IN; i += 256) {
    const float* s = coef + ((size_t)i * OUT + o) * 5;
#pragma unroll
    for (int k = 0; k < 5; ++k)
      Bt[base + (size_t)k * IN + i] = (bf16)s[k];
  }
}

// per-row LayerNorm + tanh, fp32 h -> bf16 th. One block per row (4096 cols).
__global__ __launch_bounds__(256) void k_ln_tanh(const float* __restrict__ h,
                                                 const float* __restrict__ gamma,
                                                 const float* __restrict__ beta,
                                                 bf16* __restrict__ th) {
  const int n = blockIdx.x;
  const int t = threadIdx.x;
  const float* row = h + (size_t)n * DIM_H;

  float4 v[4];
  float s1 = 0.f, s2 = 0.f;
#pragma unroll
  for (int j = 0; j < 4; ++j) {
    v[j] = *(const float4*)(row + t * 16 + j * 4);
    s1 += v[j].x + v[j].y + v[j].z + v[j].w;
    s2 += v[j].x * v[j].x + v[j].y * v[j].y + v[j].z * v[j].z + v[j].w * v[j].w;
  }
#pragma unroll
  for (int off = 32; off >= 1; off >>= 1) {
    s1 += __shfl_xor(s1, off);
    s2 += __shfl_xor(s2, off);
  }
  __shared__ float red[8];
  if ((t & 63) == 0) { red[(t >> 6) * 2] = s1; red[(t >> 6) * 2 + 1] = s2; }
  __syncthreads();
  const float S1 = red[0] + red[2] + red[4] + red[6];
  const float S2 = red[1] + red[3] + red[5] + red[7];
  const float mu   = S1 * (1.f / DIM_H);
  const float var  = S2 * (1.f / DIM_H) - mu * mu;
  const float rstd = rsqrtf(var + 1e-5f);

  float tmp[16];
#pragma unroll
  for (int j = 0; j < 4; ++j) {
    const float4 g = *(const float4*)(gamma + t * 16 + j * 4);
    const float4 b = *(const float4*)(beta  + t * 16 + j * 4);
    tmp[j * 4 + 0] = tanhf((v[j].x - mu) * rstd * g.x + b.x);
    tmp[j * 4 + 1] = tanhf((v[j].y - mu) * rstd * g.y + b.y);
    tmp[j * 4 + 2] = tanhf((v[j].z - mu) * rstd * g.z + b.z);
    tmp[j * 4 + 3] = tanhf((v[j].w - mu) * rstd * g.w + b.w);
  }
  bf16x8 w0, w1;
#pragma unroll
  for (int j = 0; j < 8; ++j) { w0[j] = (bf16)tmp[j]; w1[j] = (bf16)tmp[8 + j]; }
  bf16* o = th + (size_t)n * DIM_H + t * 16;
  *(bf16x8*)o       = w0;
  *(bf16x8*)(o + 8) = w1;
}

// ---------------------------------------------------------------- fused KAN GEMM
// C[M][NN] = sum_kcol A[M][kcol] * Bt[NN][kcol],  kcol = kidx*IND + i,
// A generated on the fly: A[m][kidx*IND+i] = T_kidx(X[m][i]).
// 128x128 tile, BK=32, 4 waves (2x2), mfma_f32_16x16x32_bf16, double-buffered LDS.
template <int IND>
__global__ __launch_bounds__(256) void k_kan_gemm(const bf16* __restrict__ X,
                                                  const bf16* __restrict__ Bt,
                                                  float* __restrict__ C,
                                                  const int NN) {
  constexpr int K  = 5 * IND;
  constexpr int KT = K / 32;

  __shared__ bf16 As[2][128][32];
  __shared__ bf16 Bs[2][128][32];

  const int tid  = threadIdx.x;
  const int lane = tid & 63;
  const int wv   = tid >> 6;
  const int wr   = wv >> 1;
  const int wc   = wv & 1;
  const int m0   = blockIdx.y * 128;
  const int n0   = blockIdx.x * 128;

  const int arow = tid >> 1;          // 0..127
  const int acol = (tid & 1) * 16;    // 0 or 16
  const int frow = lane & 15;         // fragment row/col
  const int fko  = (lane >> 4) * 8;   // fragment k offset

  f32x4 acc[4][4];
#pragma unroll
  for (int m = 0; m < 4; ++m)
#pragma unroll
    for (int n = 0; n < 4; ++n)
      acc[m][n] = (f32x4){0.f, 0.f, 0.f, 0.f};

  const bf16* aptr = X + (size_t)(m0 + arow) * IND + acol;

  auto stageB = [&](int b, int kt) {
    const bf16* s0 = Bt + (size_t)(n0 + (tid >> 2)) * K + kt * 32 + (tid & 3) * 8;
    bf16* l0 = &Bs[b][0][0] + tid * 8;     // linear dest: base + lane*16B (wave-uniform base)
    gload_lds16(s0, l0);
    gload_lds16(s0 + (size_t)64 * K, l0 + 2048);
  };
  auto loadA = [&](int kt, bf16x8& r0, bf16x8& r1) {
    const bf16* s = aptr + (kt * 32) % IND;
    r0 = *(const bf16x8*)s;
    r1 = *(const bf16x8*)(s + 8);
  };
  auto writeA = [&](int b, int kt, bf16x8 r0, bf16x8 r1) {
    const int kidx = (kt * 32) / IND;   // block-uniform
    bf16x8 w0, w1;
#pragma unroll
    for (int j = 0; j < 8; ++j) {
      w0[j] = (bf16)cheb_eval((float)r0[j], kidx);
      w1[j] = (bf16)cheb_eval((float)r1[j], kidx);
    }
    *(bf16x8*)&As[b][arow][acol]     = w0;
    *(bf16x8*)&As[b][arow][acol + 8] = w1;
  };

  // prologue: tile 0 -> buffer 0
  {
    stageB(0, 0);
    bf16x8 r0, r1;
    loadA(0, r0, r1);
    writeA(0, 0, r0, r1);
  }

  int cur = 0;
  for (int kt = 0; kt < KT; ++kt) {
    __syncthreads();                       // buf[cur] ready (vm+lgkm drained)
    bf16x8 r0, r1;
    const bool pre = (kt + 1 < KT);
    if (pre) {
      stageB(cur ^ 1, kt + 1);             // async B -> LDS (next buffer)
      loadA(kt + 1, r0, r1);               // issue A global loads early (T14)
    }

    bf16x8 af[4], bfr[4];
#pragma unroll
    for (int m = 0; m < 4; ++m)
      af[m] = *(const bf16x8*)&As[cur][wr * 64 + m * 16 + frow][fko];
#pragma unroll
    for (int n = 0; n < 4; ++n)
      bfr[n] = *(const bf16x8*)&Bs[cur][wc * 64 + n * 16 + frow][fko];

#pragma unroll
    for (int m = 0; m < 4; ++m)
#pragma unroll
      for (int n = 0; n < 4; ++n)
        acc[m][n] = __builtin_amdgcn_mfma_f32_16x16x32_bf16(af[m], bfr[n], acc[m][n], 0, 0, 0);

    if (pre) writeA(cur ^ 1, kt + 1, r0, r1);  // cheb + LDS write late
    cur ^= 1;
  }

  const int crow0 = m0 + wr * 64 + ((lane >> 4) << 2);
  const int ccol0 = n0 + wc * 64 + (lane & 15);
#pragma unroll
  for (int m = 0; m < 4; ++m)
#pragma unroll
    for (int j = 0; j < 4; ++j) {
      float* p = C + (size_t)(crow0 + m * 16 + j) * NN + ccol0;
#pragma unroll
      for (int n = 0; n < 4; ++n)
        p[n * 16] = acc[m][n][j];
    }
}

// ---------------------------------------------------------------- launch

extern "C" void kernel_launch(void* const* d_in, const int* in_sizes, int n_in,
                              void* d_out, int out_size, void* d_ws, size_t ws_size,
                              hipStream_t stream) {
  const float* x         = (const float*)d_in[0];
  const float* coef_fc   = (const float*)d_in[1];
  const float* coef_proj = (const float*)d_in[2];
  const float* gamma     = (const float*)d_in[3];
  const float* beta      = (const float*)d_in[4];
  float* out = (float*)d_out;

  // workspace layout (302 MB total)
  bf16*  xt = (bf16*)d_ws;                         // [8192][1024]  bf16
  bf16*  B1 = xt + (size_t)NR * DIM_D;             // [4096][5120]  bf16 (k-major K)
  float* h  = (float*)(B1 + (size_t)DIM_H * 5 * DIM_D); // [8192][4096] fp32
  bf16*  th = (bf16*)(h + (size_t)NR * DIM_H);     // [8192][4096]  bf16
  bf16*  B2 = th + (size_t)NR * DIM_H;             // [1024][20480] bf16 (k-major K)

  k_tanh_x<<<NR * DIM_D / 1024, 256, 0, stream>>>(x, xt);
  k_prep_w<<<DIM_H, 256, 0, stream>>>(coef_fc, B1, DIM_D, DIM_H);
  k_prep_w<<<DIM_D, 256, 0, stream>>>(coef_proj, B2, DIM_H, DIM_D);

  k_kan_gemm<DIM_D><<<dim3(DIM_H / 128, NR / 128), 256, 0, stream>>>(xt, B1, h, DIM_H);
  k_ln_tanh<<<NR, 256, 0, stream>>>(h, gamma, beta, th);
  k_kan_gemm<DIM_H><<<dim3(DIM_D / 128, NR / 128), 256, 0, stream>>>(th, B2, out, DIM_D);
}

// Round 3
// 1180.991 us; speedup vs baseline: 1.8946x; 1.8946x over previous
//
#include <hip/hip_runtime.h>
#include <hip/hip_bf16.h>
#include <cstdint>
#include <cstddef>

typedef __bf16 bf16;
typedef __attribute__((ext_vector_type(4))) __bf16 bf16x4;
typedef __attribute__((ext_vector_type(8))) __bf16 bf16x8;
typedef __attribute__((ext_vector_type(4))) float f32x4;

#define NR 8192      // B*S rows
#define DIM_D 1024
#define DIM_H 4096

// ---------------------------------------------------------------- helpers

__device__ __forceinline__ void gload_lds16(const void* g, void* l) {
  __builtin_amdgcn_global_load_lds(
      (const __attribute__((address_space(1))) void*)g,
      (__attribute__((address_space(3))) void*)l, 16, 0, 0);
}

// T_{dd+1}(x) closed-form, dd in 1..3 (dd==0 handled as identity copy)
__device__ __forceinline__ float chebd(float f, int dd) {
  const float f2 = f * f;
  if (dd == 1) return 2.0f * f2 - 1.0f;                 // T2
  if (dd == 2) return f * (4.0f * f2 - 3.0f);           // T3
  return 8.0f * f2 * (f2 - 1.0f) + 1.0f;                // T4
}

// ---------------------------------------------------------------- prep kernels

// xt = tanh(x), fp32 -> bf16
__global__ __launch_bounds__(256) void k_tanh_x(const float* __restrict__ x,
                                                bf16* __restrict__ xt) {
  const size_t i = ((size_t)blockIdx.x * 256 + threadIdx.x) * 4;
  const float4 v = *(const float4*)(x + i);
  bf16x4 r;
  r[0] = (bf16)tanhf(v.x);
  r[1] = (bf16)tanhf(v.y);
  r[2] = (bf16)tanhf(v.z);
  r[3] = (bf16)tanhf(v.w);
  *(bf16x4*)(xt + i) = r;
}

// Permuted-B prep + bias fold.
// K-order: kt = chunk*4 + dd  (dd=0..3 <-> degree 1..4), i = chunk*32 + q*8 + j.
// Bp tile (nb, kt) of 4096 elems, elem = q*1024 + r*8 + j  (r = o&127).
// bias[o] = sum_i coef[i][o][0]   (T0 == 1).
template <int IN, int OUT>
__global__ __launch_bounds__(256) void k_prep(const float* __restrict__ coef,
                                              bf16* __restrict__ Bp,
                                              float* __restrict__ bias) {
  const int o  = blockIdx.x;
  const int nb = o >> 7;
  const int r  = o & 127;
  constexpr int KT = (IN / 32) * 4;
  const int tid = threadIdx.x;

  float bacc = 0.f;
  for (int i8 = tid; i8 < IN / 8; i8 += 256) {
    const int chunk = i8 >> 2;
    const int q     = i8 & 3;
    float c[8][5];
#pragma unroll
    for (int j = 0; j < 8; ++j) {
      const float* s = coef + ((size_t)(i8 * 8 + j) * OUT + o) * 5;
#pragma unroll
      for (int k = 0; k < 5; ++k) c[j][k] = s[k];
      bacc += c[j][0];
    }
#pragma unroll
    for (int dd = 0; dd < 4; ++dd) {
      bf16x8 w;
#pragma unroll
      for (int j = 0; j < 8; ++j) w[j] = (bf16)c[j][dd + 1];
      const size_t tile = (size_t)nb * KT + chunk * 4 + dd;
      *(bf16x8*)(Bp + tile * 4096 + q * 1024 + r * 8) = w;
    }
  }
#pragma unroll
  for (int off = 32; off >= 1; off >>= 1) bacc += __shfl_xor(bacc, off);
  __shared__ float rb[4];
  if ((tid & 63) == 0) rb[tid >> 6] = bacc;
  __syncthreads();
  if (tid == 0) bias[o] = rb[0] + rb[1] + rb[2] + rb[3];
}

// per-row LayerNorm + tanh, fp32 h -> bf16 th. One block per row (4096 cols).
__global__ __launch_bounds__(256) void k_ln_tanh(const float* __restrict__ h,
                                                 const float* __restrict__ gamma,
                                                 const float* __restrict__ beta,
                                                 bf16* __restrict__ th) {
  const int n = blockIdx.x;
  const int t = threadIdx.x;
  const float* row = h + (size_t)n * DIM_H;

  float4 v[4];
  float s1 = 0.f, s2 = 0.f;
#pragma unroll
  for (int j = 0; j < 4; ++j) {
    v[j] = *(const float4*)(row + t * 16 + j * 4);
    s1 += v[j].x + v[j].y + v[j].z + v[j].w;
    s2 += v[j].x * v[j].x + v[j].y * v[j].y + v[j].z * v[j].z + v[j].w * v[j].w;
  }
#pragma unroll
  for (int off = 32; off >= 1; off >>= 1) {
    s1 += __shfl_xor(s1, off);
    s2 += __shfl_xor(s2, off);
  }
  __shared__ float red[8];
  if ((t & 63) == 0) { red[(t >> 6) * 2] = s1; red[(t >> 6) * 2 + 1] = s2; }
  __syncthreads();
  const float S1 = red[0] + red[2] + red[4] + red[6];
  const float S2 = red[1] + red[3] + red[5] + red[7];
  const float mu   = S1 * (1.f / DIM_H);
  const float var  = S2 * (1.f / DIM_H) - mu * mu;
  const float rstd = rsqrtf(var + 1e-5f);

  float tmp[16];
#pragma unroll
  for (int j = 0; j < 4; ++j) {
    const float4 g = *(const float4*)(gamma + t * 16 + j * 4);
    const float4 b = *(const float4*)(beta  + t * 16 + j * 4);
    tmp[j * 4 + 0] = tanhf((v[j].x - mu) * rstd * g.x + b.x);
    tmp[j * 4 + 1] = tanhf((v[j].y - mu) * rstd * g.y + b.y);
    tmp[j * 4 + 2] = tanhf((v[j].z - mu) * rstd * g.z + b.z);
    tmp[j * 4 + 3] = tanhf((v[j].w - mu) * rstd * g.w + b.w);
  }
  bf16x8 w0, w1;
#pragma unroll
  for (int j = 0; j < 8; ++j) { w0[j] = (bf16)tmp[j]; w1[j] = (bf16)tmp[8 + j]; }
  bf16* o = th + (size_t)n * DIM_H + t * 16;
  *(bf16x8*)o       = w0;
  *(bf16x8*)(o + 8) = w1;
}

// ---------------------------------------------------------------- fused KAN GEMM
// C = cheb(X) * Bp^T with degree-0 folded into bias (added when bias!=null).
// 128x128 tile, BK=32, 4 waves (2x2). Quarter-major LDS [q][128][8] (bank-
// conflict-free b128 reads), B pre-permuted so global_load_lds lands linear.
template <int IND>
__global__ __launch_bounds__(256, 3) void k_kan_gemm(const bf16* __restrict__ X,
                                                     const bf16* __restrict__ Bp,
                                                     float* __restrict__ C,
                                                     const float* __restrict__ bias,
                                                     const int NN, const int ktChunk) {
  constexpr int KTtot = (IND / 32) * 4;

  __shared__ bf16 As[2][4096];
  __shared__ bf16 Bs[2][4096];

  const int tid  = threadIdx.x;
  const int lane = tid & 63;
  const int wv   = tid >> 6;
  const int wr   = wv >> 1;
  const int wc   = wv & 1;
  const int m0   = blockIdx.y * 128;
  const int n0   = blockIdx.x * 128;
  const int ktB  = blockIdx.z * ktChunk;
  const int ktE  = ktB + ktChunk;
  float* Cz = C + (size_t)blockIdx.z * NR * NN;

  const int arow = tid >> 1;          // 0..127
  const int qa   = (tid & 1) * 2;     // quarter pair 0/2
  const int fr   = lane & 15;
  const int q4   = lane >> 4;         // 0..3

  f32x4 acc[4][4];
#pragma unroll
  for (int m = 0; m < 4; ++m)
#pragma unroll
    for (int n = 0; n < 4; ++n)
      acc[m][n] = (f32x4){0.f, 0.f, 0.f, 0.f};

  const bf16* aptr = X + (size_t)(m0 + arow) * IND + qa * 8;
  const size_t tileBase = (size_t)blockIdx.x * KTtot;

  auto stageB = [&](int b, int kt) {
    const bf16* s = Bp + (tileBase + kt) * 4096 + tid * 8;
    bf16* l = &Bs[b][0] + tid * 8;
    gload_lds16(s, l);
    gload_lds16(s + 2048, l + 2048);
  };
  auto writeA = [&](int b, int dd, bf16x8 x0, bf16x8 x1) {
    bf16x8 w0, w1;
    if (dd == 0) { w0 = x0; w1 = x1; }
    else {
#pragma unroll
      for (int j = 0; j < 8; ++j) {
        w0[j] = (bf16)chebd((float)x0[j], dd);
        w1[j] = (bf16)chebd((float)x1[j], dd);
      }
    }
    *(bf16x8*)&As[b][qa * 1024 + arow * 8]       = w0;
    *(bf16x8*)&As[b][(qa + 1) * 1024 + arow * 8] = w1;
  };

  bf16x8 xb0, xb1;
  // prologue: kt = ktB (chunk boundary by construction)
  {
    const bf16* s = aptr + (ktB >> 2) * 32;
    xb0 = *(const bf16x8*)s;
    xb1 = *(const bf16x8*)(s + 8);   // second half of this thread's 16-elem span
    stageB(0, ktB);
    writeA(0, 0, xb0, xb1);
  }

  int cur = 0;
  for (int kt = ktB; kt < ktE; ++kt) {
    __syncthreads();                         // buf[cur] ready
    const bool pre = (kt + 1 < ktE);
    const int dd1  = (kt + 1) & 3;
    bf16x8 n0r, n1r;
    if (pre) {
      stageB(cur ^ 1, kt + 1);               // async B -> LDS (next buffer)
      if (dd1 == 0) {                        // new chunk: issue A loads early
        const bf16* s = aptr + ((kt + 1) >> 2) * 32;
        n0r = *(const bf16x8*)s;
        n1r = *(const bf16x8*)(s + 8);       // (was s+16: quarter-misaligned)
      }
    }

    bf16x8 af[4], bfr[4];
#pragma unroll
    for (int m = 0; m < 4; ++m)
      af[m] = *(const bf16x8*)&As[cur][q4 * 1024 + (wr * 64 + m * 16 + fr) * 8];
#pragma unroll
    for (int n = 0; n < 4; ++n)
      bfr[n] = *(const bf16x8*)&Bs[cur][q4 * 1024 + (wc * 64 + n * 16 + fr) * 8];

#pragma unroll
    for (int m = 0; m < 4; ++m)
#pragma unroll
      for (int n = 0; n < 4; ++n)
        acc[m][n] = __builtin_amdgcn_mfma_f32_16x16x32_bf16(af[m], bfr[n], acc[m][n], 0, 0, 0);

    if (pre) {
      if (dd1 == 0) { xb0 = n0r; xb1 = n1r; }
      writeA(cur ^ 1, dd1, xb0, xb1);        // cheb + LDS write late
    }
    cur ^= 1;
  }

  const int crow0 = m0 + wr * 64 + ((lane >> 4) << 2);
  const int ccol0 = n0 + wc * 64 + (lane & 15);
  float bv[4] = {0.f, 0.f, 0.f, 0.f};
  if (bias) {
#pragma unroll
    for (int n = 0; n < 4; ++n) bv[n] = bias[ccol0 + n * 16];
  }
#pragma unroll
  for (int m = 0; m < 4; ++m)
#pragma unroll
    for (int j = 0; j < 4; ++j) {
      float* p = Cz + (size_t)(crow0 + m * 16 + j) * NN + ccol0;
#pragma unroll
      for (int n = 0; n < 4; ++n)
        p[n * 16] = acc[m][n][j] + bv[n];
    }
}

// out[row][c] = p0 + p1 + bias2[c]; one block per row of 1024 fp32.
__global__ __launch_bounds__(256) void k_reduce2(const float* __restrict__ p0,
                                                 const float* __restrict__ p1,
                                                 const float* __restrict__ bias,
                                                 float* __restrict__ out) {
  const size_t base = (size_t)blockIdx.x * 1024 + threadIdx.x * 4;
  const float4 a = *(const float4*)(p0 + base);
  const float4 b = *(const float4*)(p1 + base);
  const float4 c = *(const float4*)(bias + threadIdx.x * 4);
  float4 r;
  r.x = a.x + b.x + c.x;
  r.y = a.y + b.y + c.y;
  r.z = a.z + b.z + c.z;
  r.w = a.w + b.w + c.w;
  *(float4*)(out + base) = r;
}

// ---------------------------------------------------------------- launch

extern "C" void kernel_launch(void* const* d_in, const int* in_sizes, int n_in,
                              void* d_out, int out_size, void* d_ws, size_t ws_size,
                              hipStream_t stream) {
  const float* x         = (const float*)d_in[0];
  const float* coef_fc   = (const float*)d_in[1];
  const float* coef_proj = (const float*)d_in[2];
  const float* gamma     = (const float*)d_in[3];
  const float* beta      = (const float*)d_in[4];
  float* out = (float*)d_out;

  // workspace layout (~272 MB peak)
  char* w = (char*)d_ws;
  bf16*  B1p   = (bf16*)w;                          w += (size_t)DIM_H * 4 * DIM_D * 2;  // 32 MB
  bf16*  B2p   = (bf16*)w;                          w += (size_t)DIM_D * 4 * DIM_H * 2;  // 32 MB
  float* bias1 = (float*)w;                         w += 64 * 1024;
  float* bias2 = (float*)w;                         w += 64 * 1024;
  bf16*  xt    = (bf16*)w;                          w += (size_t)NR * DIM_D * 2;         // 16 MB
  float* h     = (float*)w;                         w += (size_t)NR * DIM_H * 4;         // 128 MB
  bf16*  th    = (bf16*)w;                          w += (size_t)NR * DIM_H * 2;         // 64 MB
  float* part  = h;  // partials (2 x 32 MB) overlay h, which is dead after ln_tanh

  k_tanh_x<<<NR * DIM_D / 1024, 256, 0, stream>>>(x, xt);
  k_prep<DIM_D, DIM_H><<<DIM_H, 256, 0, stream>>>(coef_fc, B1p, bias1);
  k_prep<DIM_H, DIM_D><<<DIM_D, 256, 0, stream>>>(coef_proj, B2p, bias2);

  // GEMM1: [8192 x 4096(K')] -> h [8192][4096], bias folded in epilogue
  k_kan_gemm<DIM_D><<<dim3(DIM_H / 128, NR / 128, 1), 256, 0, stream>>>(
      xt, B1p, h, bias1, DIM_H, (DIM_D / 32) * 4);

  k_ln_tanh<<<NR, 256, 0, stream>>>(h, gamma, beta, th);

  // GEMM2: split-K x2 -> partials, then reduce(+bias2) -> out
  k_kan_gemm<DIM_H><<<dim3(DIM_D / 128, NR / 128, 2), 256, 0, stream>>>(
      th, B2p, part, nullptr, DIM_D, (DIM_H / 32) * 4 / 2);
  k_reduce2<<<NR, 256, 0, stream>>>(part, part + (size_t)NR * DIM_D, bias2, out);
}

// Round 4
// 943.016 us; speedup vs baseline: 2.3727x; 1.2524x over previous
//
#include <hip/hip_runtime.h>
#include <hip/hip_bf16.h>
#include <cstdint>
#include <cstddef>

typedef __bf16 bf16;
typedef __attribute__((ext_vector_type(4))) __bf16 bf16x4;
typedef __attribute__((ext_vector_type(8))) __bf16 bf16x8;
typedef __attribute__((ext_vector_type(4))) float f32x4;

#define NR 8192      // B*S rows
#define DIM_D 1024
#define DIM_H 4096

// ---------------------------------------------------------------- helpers

__device__ __forceinline__ void gload_lds16(const void* g, void* l) {
  __builtin_amdgcn_global_load_lds(
      (const __attribute__((address_space(1))) void*)g,
      (__attribute__((address_space(3))) void*)l, 16, 0, 0);
}

#define BAR()  __builtin_amdgcn_s_barrier()
#define WLG0() asm volatile("s_waitcnt lgkmcnt(0)" ::: "memory")
#define WVM0() asm volatile("s_waitcnt vmcnt(0)" ::: "memory")
#define WVM4() asm volatile("s_waitcnt vmcnt(4)" ::: "memory")
#define WVM6() asm volatile("s_waitcnt vmcnt(6)" ::: "memory")
#define PRIO1() __builtin_amdgcn_s_setprio(1)
#define PRIO0() __builtin_amdgcn_s_setprio(0)

// ---------------------------------------------------------------- prep kernels

// xt = tanh(x), fp32 -> bf16
__global__ __launch_bounds__(256) void k_tanh_x(const float* __restrict__ x,
                                                bf16* __restrict__ xt) {
  const size_t i = ((size_t)blockIdx.x * 256 + threadIdx.x) * 4;
  const float4 v = *(const float4*)(x + i);
  bf16x4 r;
  r[0] = (bf16)tanhf(v.x);
  r[1] = (bf16)tanhf(v.y);
  r[2] = (bf16)tanhf(v.z);
  r[3] = (bf16)tanhf(v.w);
  *(bf16x4*)(xt + i) = r;
}

// Permuted-B prep + bias fold, 256-col tiles for the 8-phase GEMM.
// Tile (nb = o>>8, kt = chunk*2 + dp) holds 64(K) x 256(col) bf16, flat elem
//   = ksub*2048 + r*8 + j,  ksub = dh*4 + q,  r = o&255,
// where input col i = chunk*32 + q*8 + j and coefficient degree k = dp*2+dh+1.
// bias[o] = sum_i coef[i][o][0]  (T0 == 1).
template <int IN, int OUT>
__global__ __launch_bounds__(256) void k_prep(const float* __restrict__ coef,
                                              bf16* __restrict__ Bp,
                                              float* __restrict__ bias) {
  const int o  = blockIdx.x;
  const int nb = o >> 8;
  const int r  = o & 255;
  constexpr int KT = (IN / 32) * 2;
  const int tid = threadIdx.x;

  float bacc = 0.f;
  for (int i8 = tid; i8 < IN / 8; i8 += 256) {
    const int chunk = i8 >> 2;
    const int q     = i8 & 3;
    float c[8][5];
#pragma unroll
    for (int j = 0; j < 8; ++j) {
      const float* s = coef + ((size_t)(i8 * 8 + j) * OUT + o) * 5;
#pragma unroll
      for (int k = 0; k < 5; ++k) c[j][k] = s[k];
      bacc += c[j][0];
    }
#pragma unroll
    for (int k = 1; k <= 4; ++k) {
      const int dp = (k - 1) >> 1;
      const int dh = (k - 1) & 1;
      bf16x8 w;
#pragma unroll
      for (int j = 0; j < 8; ++j) w[j] = (bf16)c[j][k];
      *(bf16x8*)(Bp + ((size_t)nb * KT + chunk * 2 + dp) * 16384 +
                 (dh * 4 + q) * 2048 + (size_t)r * 8) = w;
    }
  }
#pragma unroll
  for (int off = 32; off >= 1; off >>= 1) bacc += __shfl_xor(bacc, off);
  __shared__ float rb[4];
  if ((tid & 63) == 0) rb[tid >> 6] = bacc;
  __syncthreads();
  if (tid == 0) bias[o] = rb[0] + rb[1] + rb[2] + rb[3];
}

// per-row LayerNorm + tanh, fp32 h -> bf16 th. One block per row (4096 cols).
__global__ __launch_bounds__(256) void k_ln_tanh(const float* __restrict__ h,
                                                 const float* __restrict__ gamma,
                                                 const float* __restrict__ beta,
                                                 bf16* __restrict__ th) {
  const int n = blockIdx.x;
  const int t = threadIdx.x;
  const float* row = h + (size_t)n * DIM_H;

  float4 v[4];
  float s1 = 0.f, s2 = 0.f;
#pragma unroll
  for (int j = 0; j < 4; ++j) {
    v[j] = *(const float4*)(row + t * 16 + j * 4);
    s1 += v[j].x + v[j].y + v[j].z + v[j].w;
    s2 += v[j].x * v[j].x + v[j].y * v[j].y + v[j].z * v[j].z + v[j].w * v[j].w;
  }
#pragma unroll
  for (int off = 32; off >= 1; off >>= 1) {
    s1 += __shfl_xor(s1, off);
    s2 += __shfl_xor(s2, off);
  }
  __shared__ float red[8];
  if ((t & 63) == 0) { red[(t >> 6) * 2] = s1; red[(t >> 6) * 2 + 1] = s2; }
  __syncthreads();
  const float S1 = red[0] + red[2] + red[4] + red[6];
  const float S2 = red[1] + red[3] + red[5] + red[7];
  const float mu   = S1 * (1.f / DIM_H);
  const float var  = S2 * (1.f / DIM_H) - mu * mu;
  const float rstd = rsqrtf(var + 1e-5f);

  float tmp[16];
#pragma unroll
  for (int j = 0; j < 4; ++j) {
    const float4 g = *(const float4*)(gamma + t * 16 + j * 4);
    const float4 b = *(const float4*)(beta  + t * 16 + j * 4);
    tmp[j * 4 + 0] = tanhf((v[j].x - mu) * rstd * g.x + b.x);
    tmp[j * 4 + 1] = tanhf((v[j].y - mu) * rstd * g.y + b.y);
    tmp[j * 4 + 2] = tanhf((v[j].z - mu) * rstd * g.z + b.z);
    tmp[j * 4 + 3] = tanhf((v[j].w - mu) * rstd * g.w + b.w);
  }
  bf16x8 w0, w1;
#pragma unroll
  for (int j = 0; j < 8; ++j) { w0[j] = (bf16)tmp[j]; w1[j] = (bf16)tmp[8 + j]; }
  bf16* o = th + (size_t)n * DIM_H + t * 16;
  *(bf16x8*)o       = w0;
  *(bf16x8*)(o + 8) = w1;
}

// ---------------------------------------------------------------- 8-phase fused KAN GEMM
// C = cheb(X) * Bp^T, deg-0 folded into bias. 256x256 tile, BK=64, 8 waves
// (2M x 4N), double-buffered 128 KiB LDS, counted-vmcnt pipeline (T3+T4), T5.
// K-order: chunk-group g = 32 input cols -> 2 K-tiles (deg 1,2 | deg 3,4).
// LDS layout per tile: [ksub 0..7][row 0..255][8] (b128 reads 2-way = free).
template <int IND, int NZ>
__global__ __launch_bounds__(512, 2) void k_gemm8(const bf16* __restrict__ X,
                                                  const bf16* __restrict__ Bp,
                                                  float* __restrict__ C,
                                                  const float* __restrict__ bias,
                                                  const int NN) {
  constexpr int NCH = IND / 32 / NZ;       // chunk-groups per z-slice
  constexpr int KTt = (IND / 32) * 2;      // total 64-K tiles per n-block

  __shared__ bf16 Ash[2][16384];
  __shared__ bf16 Bsh[2][16384];

  const int tid  = threadIdx.x;
  const int lane = tid & 63;
  const int wid  = tid >> 6;
  const int wm   = wid >> 2;               // 0..1
  const int wn   = wid & 3;                // 0..3
  const int fr   = lane & 15;
  const int kq   = lane >> 4;              // 0..3
  const int m0   = blockIdx.y * 256;
  const int n0   = blockIdx.x * 256;
  const int zc0  = blockIdx.z * NCH;       // first chunk (global) of this z

  const int ar = tid >> 1;                 // A-stage row 0..255
  const int aq = (tid & 1) * 2;            // A-stage q base 0/2

  f32x4 acc[8][4];
#pragma unroll
  for (int m = 0; m < 8; ++m)
#pragma unroll
    for (int n = 0; n < 4; ++n) acc[m][n] = (f32x4){0.f, 0.f, 0.f, 0.f};

  const bf16* xp = X + (size_t)(m0 + ar) * IND + (size_t)zc0 * 32 + aq * 8;
  const size_t bt0 = (size_t)blockIdx.x * KTt + (size_t)zc0 * 2;

  bf16x8 xn0, xn1;     // staging chunk's x (16 elems/thread)
  float  xf[16];       // f32 copies for cheb
  bf16x8 afr[4], bfr[4];

  auto stB = [&](int d, int kh, int ktl) {
    const bf16* s = Bp + (bt0 + (size_t)ktl) * 16384 + kh * 8192 + tid * 8;
    bf16* l = &Bsh[d][kh * 8192 + tid * 8];
    gload_lds16(s, l);
    gload_lds16(s + 4096, l + 4096);
  };
  auto ldx = [&](int c) {
    const bf16* s = xp + (size_t)c * 32;
    xn0 = *(const bf16x8*)s;
    xn1 = *(const bf16x8*)(s + 8);
  };
  auto cvtxf = [&]() {
#pragma unroll
    for (int j = 0; j < 8; ++j) { xf[j] = (float)xn0[j]; xf[8 + j] = (float)xn1[j]; }
  };
  auto wA = [&](int d, int dh, bf16x8 w0, bf16x8 w1) {
    *(bf16x8*)&Ash[d][(dh * 4 + aq) * 2048 + ar * 8]       = w0;
    *(bf16x8*)&Ash[d][(dh * 4 + aq + 1) * 2048 + ar * 8]   = w1;
  };
  auto chebw = [&](int deg, bf16x8& w0, bf16x8& w1) {
#pragma unroll
    for (int j = 0; j < 8; ++j) {
      const float a = xf[j], b = xf[8 + j];
      const float a2 = a * a, b2 = b * b;
      float ra, rb;
      if (deg == 2)      { ra = 2.f * a2 - 1.f;            rb = 2.f * b2 - 1.f; }
      else if (deg == 3) { ra = a * (4.f * a2 - 3.f);      rb = b * (4.f * b2 - 3.f); }
      else               { ra = 8.f * a2 * (a2 - 1.f) + 1.f; rb = 8.f * b2 * (b2 - 1.f) + 1.f; }
      w0[j] = (bf16)ra; w1[j] = (bf16)rb;
    }
  };
  auto rdB = [&](int d, int kh) {
#pragma unroll
    for (int n = 0; n < 4; ++n)
      bfr[n] = *(const bf16x8*)&Bsh[d][(kh * 4 + kq) * 2048 + (wn * 64 + n * 16 + fr) * 8];
  };
  auto rdA = [&](int d, int kh, int mh) {
#pragma unroll
    for (int m = 0; m < 4; ++m)
      afr[m] = *(const bf16x8*)&Ash[d][(kh * 4 + kq) * 2048 + (wm * 128 + mh * 64 + m * 16 + fr) * 8];
  };
  auto mma = [&](int mh) {
#pragma unroll
    for (int m = 0; m < 4; ++m)
#pragma unroll
      for (int n = 0; n < 4; ++n)
        acc[mh * 4 + m][n] =
            __builtin_amdgcn_mfma_f32_16x16x32_bf16(afr[m], bfr[n], acc[mh * 4 + m][n], 0, 0, 0);
  };

  // ---- prologue: stage K-tiles 0,1 (B via gload_lds, A via cheb ds_write)
  ldx(0);
  stB(0, 0, 0); stB(0, 1, 0);
  stB(1, 0, 1); stB(1, 1, 1);
  cvtxf();
  wA(0, 0, xn0, xn1);                                   // t0 deg1 (copy)
  { bf16x8 w0, w1; chebw(2, w0, w1); wA(0, 1, w0, w1); } // t0 deg2
  { bf16x8 w0, w1; chebw(3, w0, w1); wA(1, 0, w0, w1); } // t1 deg3
  { bf16x8 w0, w1; chebw(4, w0, w1); wA(1, 1, w0, w1); } // t1 deg4
  WVM0(); WLG0();
  BAR();

  // ---- main loop: group g computes K-tiles 2g (buf0), 2g+1 (buf1)
#pragma unroll 1
  for (int g = 0; g < NCH; ++g) {
    const bool st = (g + 1 < NCH);
    // P1: buf0 kh0 ml | issue x(g+1); deferred A(2g+1) deg4 write
    rdB(0, 0); rdA(0, 0, 0);
    if (g > 0) { bf16x8 w0, w1; chebw(4, w0, w1); wA(1, 1, w0, w1); }
    if (st) ldx(g + 1);
    BAR(); WLG0();
    PRIO1(); mma(0); PRIO0();
    BAR();
    // P2: buf0 kh0 mh | stage B(2g+2) kh0 -> Bsh0
    rdA(0, 0, 1);
    if (st) stB(0, 0, 2 * (g + 1));
    BAR(); WLG0();
    PRIO1(); mma(1); PRIO0();
    BAR();
    // P3: buf0 kh1 ml
    rdB(0, 1); rdA(0, 1, 0);
    BAR(); WLG0();
    PRIO1(); mma(0); PRIO0();
    BAR();
    // P4: buf0 kh1 mh | stage B(2g+2) kh1 | counted vmcnt
    rdA(0, 1, 1);
    if (st) { stB(0, 1, 2 * (g + 1)); WVM6(); } else { WVM0(); }
    BAR(); WLG0();
    PRIO1(); mma(1); PRIO0();
    BAR();
    // P5: buf1 kh0 ml | cvt x(g+1); A(2g+2) deg1 -> Ash0 kh0
    rdB(1, 0); rdA(1, 0, 0);
    if (st) { cvtxf(); wA(0, 0, xn0, xn1); }
    BAR(); WLG0();
    PRIO1(); mma(0); PRIO0();
    BAR();
    // P6: buf1 kh0 mh | A(2g+2) deg2 -> Ash0 kh1
    rdA(1, 0, 1);
    if (st) { bf16x8 w0, w1; chebw(2, w0, w1); wA(0, 1, w0, w1); }
    BAR(); WLG0();
    PRIO1(); mma(1); PRIO0();
    BAR();
    // P7: buf1 kh1 ml | A(2g+3) deg3 -> Ash1 kh0; stage B(2g+3) kh0
    rdB(1, 1); rdA(1, 1, 0);
    if (st) { bf16x8 w0, w1; chebw(3, w0, w1); wA(1, 0, w0, w1); stB(1, 0, 2 * (g + 1) + 1); }
    BAR(); WLG0();
    PRIO1(); mma(0); PRIO0();
    BAR();
    // P8: buf1 kh1 mh | stage B(2g+3) kh1 | counted vmcnt
    //     (A(2g+3) deg4 deferred to next group's P1 — region read here)
    rdA(1, 1, 1);
    if (st) { stB(1, 1, 2 * (g + 1) + 1); WVM4(); }
    BAR(); WLG0();
    PRIO1(); mma(1); PRIO0();
    BAR();
  }

  // ---- epilogue
  float bv[4] = {0.f, 0.f, 0.f, 0.f};
  const int c0 = n0 + wn * 64 + fr;
  if (bias) {
#pragma unroll
    for (int n = 0; n < 4; ++n) bv[n] = bias[c0 + n * 16];
  }
  float* Cz = C + (size_t)blockIdx.z * NR * NN;
  const int r0 = m0 + wm * 128 + kq * 4;
#pragma unroll
  for (int mi = 0; mi < 8; ++mi)
#pragma unroll
    for (int j = 0; j < 4; ++j) {
      float* p = Cz + (size_t)(r0 + mi * 16 + j) * NN + c0;
#pragma unroll
      for (int n = 0; n < 4; ++n)
        p[n * 16] = acc[mi][n][j] + bv[n];
    }
}

// out[row][c] = p0 + p1 + bias2[c]; one block per row of 1024 fp32.
__global__ __launch_bounds__(256) void k_reduce2(const float* __restrict__ p0,
                                                 const float* __restrict__ p1,
                                                 const float* __restrict__ bias,
                                                 float* __restrict__ out) {
  const size_t base = (size_t)blockIdx.x * 1024 + threadIdx.x * 4;
  const float4 a = *(const float4*)(p0 + base);
  const float4 b = *(const float4*)(p1 + base);
  const float4 c = *(const float4*)(bias + threadIdx.x * 4);
  float4 r;
  r.x = a.x + b.x + c.x;
  r.y = a.y + b.y + c.y;
  r.z = a.z + b.z + c.z;
  r.w = a.w + b.w + c.w;
  *(float4*)(out + base) = r;
}

// ---------------------------------------------------------------- launch

extern "C" void kernel_launch(void* const* d_in, const int* in_sizes, int n_in,
                              void* d_out, int out_size, void* d_ws, size_t ws_size,
                              hipStream_t stream) {
  const float* x         = (const float*)d_in[0];
  const float* coef_fc   = (const float*)d_in[1];
  const float* coef_proj = (const float*)d_in[2];
  const float* gamma     = (const float*)d_in[3];
  const float* beta      = (const float*)d_in[4];
  float* out = (float*)d_out;

  // workspace layout (~272 MB peak)
  char* w = (char*)d_ws;
  bf16*  B1p   = (bf16*)w;                          w += (size_t)DIM_H * 4 * DIM_D * 2;  // 32 MB
  bf16*  B2p   = (bf16*)w;                          w += (size_t)DIM_D * 4 * DIM_H * 2;  // 32 MB
  float* bias1 = (float*)w;                         w += 64 * 1024;
  float* bias2 = (float*)w;                         w += 64 * 1024;
  bf16*  xt    = (bf16*)w;                          w += (size_t)NR * DIM_D * 2;         // 16 MB
  float* h     = (float*)w;                         w += (size_t)NR * DIM_H * 4;         // 128 MB
  bf16*  th    = (bf16*)w;                          w += (size_t)NR * DIM_H * 2;         // 64 MB
  float* part  = h;  // partials (2 x 32 MB) overlay h, dead after ln_tanh

  k_tanh_x<<<NR * DIM_D / 1024, 256, 0, stream>>>(x, xt);
  k_prep<DIM_D, DIM_H><<<DIM_H, 256, 0, stream>>>(coef_fc, B1p, bias1);
  k_prep<DIM_H, DIM_D><<<DIM_D, 256, 0, stream>>>(coef_proj, B2p, bias2);

  // GEMM1: [8192 x 4096(K')] -> h [8192][4096], bias in epilogue
  k_gemm8<DIM_D, 1><<<dim3(DIM_H / 256, NR / 256, 1), 512, 0, stream>>>(
      xt, B1p, h, bias1, DIM_H);

  k_ln_tanh<<<NR, 256, 0, stream>>>(h, gamma, beta, th);

  // GEMM2: split-K x2 -> partials, then reduce(+bias2) -> out
  k_gemm8<DIM_H, 2><<<dim3(DIM_D / 256, NR / 256, 2), 512, 0, stream>>>(
      th, B2p, part, nullptr, DIM_D);
  k_reduce2<<<NR, 256, 0, stream>>>(part, part + (size_t)NR * DIM_D, bias2, out);
}

// Round 5
// 704.527 us; speedup vs baseline: 3.1759x; 1.3385x over previous
//
#include <hip/hip_runtime.h>
#include <hip/hip_bf16.h>
#include <cstdint>
#include <cstddef>

typedef __bf16 bf16;
typedef __attribute__((ext_vector_type(4))) __bf16 bf16x4;
typedef __attribute__((ext_vector_type(8))) __bf16 bf16x8;
typedef __attribute__((ext_vector_type(4))) float f32x4;

#define NR 8192      // B*S rows
#define DIM_D 1024
#define DIM_H 4096

// ---------------------------------------------------------------- helpers

__device__ __forceinline__ void gload_lds16(const void* g, void* l) {
  __builtin_amdgcn_global_load_lds(
      (const __attribute__((address_space(1))) void*)g,
      (__attribute__((address_space(3))) void*)l, 16, 0, 0);
}

#define BAR()  __builtin_amdgcn_s_barrier()
#define WLG0() asm volatile("s_waitcnt lgkmcnt(0)" ::: "memory")
#define WVM0() asm volatile("s_waitcnt vmcnt(0)" ::: "memory")
#define WVM4() asm volatile("s_waitcnt vmcnt(4)" ::: "memory")
#define WVM6() asm volatile("s_waitcnt vmcnt(6)" ::: "memory")
#define WVM8() asm volatile("s_waitcnt vmcnt(8)" ::: "memory")
#define PRIO1() __builtin_amdgcn_s_setprio(1)
#define PRIO0() __builtin_amdgcn_s_setprio(0)

// T_{dd+1}(x) closed-form, dd in 1..3 (dd==0 identity)
__device__ __forceinline__ float chebd(float f, int dd) {
  const float f2 = f * f;
  if (dd == 1) return 2.0f * f2 - 1.0f;                 // T2
  if (dd == 2) return f * (4.0f * f2 - 3.0f);           // T3
  return 8.0f * f2 * (f2 - 1.0f) + 1.0f;                // T4
}

// ---------------------------------------------------------------- prep kernels (shared)

// Coalesced permuted-B prep. Block = (256 outputs) x (32 inputs = 1 chunk).
// K-order: tile kt = chunk*2 + dp (dp = (k-1)>>1), elem (dh*4+q)*2048 + r*8 + j,
// dh = (k-1)&1, input i = chunk*32 + q*8 + j, r = o&255.
// bias partials: bpart[chunk][o] = sum over this chunk's i of coef[i][o][0].
template <int IN, int OUT>
__global__ __launch_bounds__(256) void k_prep_t(const float* __restrict__ coef,
                                                bf16* __restrict__ Bp,
                                                float* __restrict__ bpart) {
  constexpr int KT = (IN / 32) * 2;
  const int tid   = threadIdx.x;
  const int o     = blockIdx.x * 256 + tid;
  const int nb    = blockIdx.x;          // = o >> 8
  const int chunk = blockIdx.y;
  const int i0    = chunk * 32;

  float bacc = 0.f;
#pragma unroll
  for (int q = 0; q < 4; ++q) {
    bf16x8 w1, w2, w3, w4;
#pragma unroll
    for (int j = 0; j < 8; ++j) {
      const float* s = coef + ((size_t)(i0 + q * 8 + j) * OUT + o) * 5;
      bacc += s[0];
      w1[j] = (bf16)s[1]; w2[j] = (bf16)s[2]; w3[j] = (bf16)s[3]; w4[j] = (bf16)s[4];
    }
    bf16* base = Bp + ((size_t)nb * KT + chunk * 2) * 16384 + (size_t)tid * 8;
    *(bf16x8*)(base + (0 * 4 + q) * 2048)         = w1;   // k=1: dp0 dh0
    *(bf16x8*)(base + (1 * 4 + q) * 2048)         = w2;   // k=2: dp0 dh1
    *(bf16x8*)(base + 16384 + (0 * 4 + q) * 2048) = w3;   // k=3: dp1 dh0
    *(bf16x8*)(base + 16384 + (1 * 4 + q) * 2048) = w4;   // k=4: dp1 dh1
  }
  bpart[(size_t)chunk * OUT + o] = bacc;
}

// bias[o] = sum_p bpart[p*OUT + o]
__global__ __launch_bounds__(256) void k_bias_red(const float* __restrict__ bpart,
                                                  float* __restrict__ bias,
                                                  const int OUT, const int NP) {
  const int o = blockIdx.x * 256 + threadIdx.x;
  float s = 0.f;
  for (int p = 0; p < NP; ++p) s += bpart[(size_t)p * OUT + o];
  bias[o] = s;
}

// ---------------------------------------------------------------- expanded-A prep

// Ax[row][col'] = T_k(tanh(x[row][i])), col' = chunk*128 + (k-1)*32 + q*8 + j.
__global__ __launch_bounds__(256) void k_tanh_cheb(const float* __restrict__ x,
                                                   bf16* __restrict__ Ax) {
  const size_t base = ((size_t)blockIdx.x * 256 + threadIdx.x) * 8;
  const size_t row  = base >> 10;
  const int    i    = (int)(base & 1023);
  const float4 v0 = *(const float4*)(x + base);
  const float4 v1 = *(const float4*)(x + base + 4);
  float f[8] = {tanhf(v0.x), tanhf(v0.y), tanhf(v0.z), tanhf(v0.w),
                tanhf(v1.x), tanhf(v1.y), tanhf(v1.z), tanhf(v1.w)};
  bf16x8 w1, w2, w3, w4;
#pragma unroll
  for (int j = 0; j < 8; ++j) {
    const float a = f[j], a2 = a * a;
    w1[j] = (bf16)a;
    w2[j] = (bf16)(2.f * a2 - 1.f);
    w3[j] = (bf16)(a * (4.f * a2 - 3.f));
    w4[j] = (bf16)(8.f * a2 * (a2 - 1.f) + 1.f);
  }
  bf16* o = Ax + row * 4096 + (i >> 5) * 128 + ((i >> 3) & 3) * 8;
  *(bf16x8*)(o)      = w1;
  *(bf16x8*)(o + 32) = w2;
  *(bf16x8*)(o + 64) = w3;
  *(bf16x8*)(o + 96) = w4;
}

// LayerNorm + tanh + cheb-expand: fp32 h row -> Ax2[row][16384] (K'-permuted).
__global__ __launch_bounds__(256) void k_lntanh_cheb(const float* __restrict__ h,
                                                     const float* __restrict__ gamma,
                                                     const float* __restrict__ beta,
                                                     bf16* __restrict__ Ax) {
  const int n = blockIdx.x;
  const int t = threadIdx.x;
  const float* row = h + (size_t)n * DIM_H;

  float4 v[4];
  float s1 = 0.f, s2 = 0.f;
#pragma unroll
  for (int j = 0; j < 4; ++j) {
    v[j] = *(const float4*)(row + t * 16 + j * 4);
    s1 += v[j].x + v[j].y + v[j].z + v[j].w;
    s2 += v[j].x * v[j].x + v[j].y * v[j].y + v[j].z * v[j].z + v[j].w * v[j].w;
  }
#pragma unroll
  for (int off = 32; off >= 1; off >>= 1) {
    s1 += __shfl_xor(s1, off);
    s2 += __shfl_xor(s2, off);
  }
  __shared__ float red[8];
  if ((t & 63) == 0) { red[(t >> 6) * 2] = s1; red[(t >> 6) * 2 + 1] = s2; }
  __syncthreads();
  const float S1 = red[0] + red[2] + red[4] + red[6];
  const float S2 = red[1] + red[3] + red[5] + red[7];
  const float mu   = S1 * (1.f / DIM_H);
  const float var  = S2 * (1.f / DIM_H) - mu * mu;
  const float rstd = rsqrtf(var + 1e-5f);

  float f[16];
#pragma unroll
  for (int j = 0; j < 4; ++j) {
    const float4 g = *(const float4*)(gamma + t * 16 + j * 4);
    const float4 b = *(const float4*)(beta  + t * 16 + j * 4);
    f[j * 4 + 0] = tanhf((v[j].x - mu) * rstd * g.x + b.x);
    f[j * 4 + 1] = tanhf((v[j].y - mu) * rstd * g.y + b.y);
    f[j * 4 + 2] = tanhf((v[j].z - mu) * rstd * g.z + b.z);
    f[j * 4 + 3] = tanhf((v[j].w - mu) * rstd * g.w + b.w);
  }
  // i = t*16 + [0..15] -> chunk = t>>1, q0 = (t&1)*2 (+1 for high half)
  bf16* o = Ax + (size_t)n * 16384 + (t >> 1) * 128 + ((t & 1) * 2) * 8;
#pragma unroll
  for (int k = 1; k <= 4; ++k) {
    bf16x8 w0, w1;
#pragma unroll
    for (int j = 0; j < 8; ++j) {
      const float a = f[j], a2 = a * a;
      const float b = f[8 + j], b2 = b * b;
      float ra, rb;
      if (k == 1)      { ra = a;                          rb = b; }
      else if (k == 2) { ra = 2.f * a2 - 1.f;             rb = 2.f * b2 - 1.f; }
      else if (k == 3) { ra = a * (4.f * a2 - 3.f);       rb = b * (4.f * b2 - 3.f); }
      else             { ra = 8.f * a2 * (a2 - 1.f) + 1.f; rb = 8.f * b2 * (b2 - 1.f) + 1.f; }
      w0[j] = (bf16)ra; w1[j] = (bf16)rb;
    }
    *(bf16x8*)(o + (k - 1) * 32)     = w0;
    *(bf16x8*)(o + (k - 1) * 32 + 8) = w1;
  }
}

// ---------------------------------------------------------------- pure 8-phase GEMM (m201)
// C = Ax * Bp^T (+bias). 256x256, BK=64, 8 waves (2Mx4N), dbuf 128KiB LDS.
// Both operands staged via global_load_lds at kh-half granularity; counted
// vmcnt(6) at P4/P8; A(buf1,kh1) staged in the NEXT group's P1 (deferred slot).
template <int IND, int NZ>
__global__ __launch_bounds__(512, 2) void k_gemm8x(const bf16* __restrict__ Ax,
                                                   const bf16* __restrict__ Bp,
                                                   float* __restrict__ C,
                                                   const float* __restrict__ bias,
                                                   const int NN) {
  constexpr int KP  = IND * 4;             // expanded K'
  constexpr int NCH = IND / 32 / NZ;       // groups per z-slice
  constexpr int KTt = (IND / 32) * 2;      // 64-K tiles per n-block (total)

  __shared__ bf16 Ash[2][16384];
  __shared__ bf16 Bsh[2][16384];

  const int tid  = threadIdx.x;
  const int lane = tid & 63;
  const int wid  = tid >> 6;
  const int wm   = wid >> 2;
  const int wn   = wid & 3;
  const int fr   = lane & 15;
  const int kq   = lane >> 4;
  const int m0   = blockIdx.y * 256;
  const int n0   = blockIdx.x * 256;
  const int zc0  = blockIdx.z * NCH;

  f32x4 acc[8][4];
#pragma unroll
  for (int m = 0; m < 8; ++m)
#pragma unroll
    for (int n = 0; n < 4; ++n) acc[m][n] = (f32x4){0.f, 0.f, 0.f, 0.f};

  const size_t bt0 = (size_t)blockIdx.x * KTt + (size_t)zc0 * 2;
  const bf16* Az = Ax + (size_t)zc0 * 128;   // this z-slice's first col'

  const int sub = tid >> 8;                  // 0/1
  const int rA  = tid & 255;

  auto stB = [&](int d, int kh, int ktl) {
    const bf16* s = Bp + (bt0 + (size_t)ktl) * 16384 + kh * 8192 + tid * 8;
    bf16* l = &Bsh[d][kh * 8192 + tid * 8];
    gload_lds16(s, l);
    gload_lds16(s + 4096, l + 4096);
  };
  auto stA = [&](int d, int kh, int ktl) {
    const bf16* s = Az + (size_t)(m0 + rA) * KP + (size_t)ktl * 64 + kh * 32 + sub * 8;
    bf16* l = &Ash[d][(kh * 4 + sub) * 2048 + rA * 8];
    gload_lds16(s, l);
    gload_lds16(s + 16, l + 4096);
  };

  bf16x8 afr[4], bfr[4];
  auto rdB = [&](int d, int kh) {
#pragma unroll
    for (int n = 0; n < 4; ++n)
      bfr[n] = *(const bf16x8*)&Bsh[d][(kh * 4 + kq) * 2048 + (wn * 64 + n * 16 + fr) * 8];
  };
  auto rdA = [&](int d, int kh, int mh) {
#pragma unroll
    for (int m = 0; m < 4; ++m)
      afr[m] = *(const bf16x8*)&Ash[d][(kh * 4 + kq) * 2048 + (wm * 128 + mh * 64 + m * 16 + fr) * 8];
  };
  auto mma = [&](int mh) {
#pragma unroll
    for (int m = 0; m < 4; ++m)
#pragma unroll
      for (int n = 0; n < 4; ++n)
        acc[mh * 4 + m][n] =
            __builtin_amdgcn_mfma_f32_16x16x32_bf16(afr[m], bfr[n], acc[mh * 4 + m][n], 0, 0, 0);
  };

  // prologue: tiles 0 (buf0) and 1 (buf1), 16 gloads; drain tile0.
  stA(0, 0, 0); stA(0, 1, 0); stB(0, 0, 0); stB(0, 1, 0);
  stA(1, 0, 1); stA(1, 1, 1); stB(1, 0, 1); stB(1, 1, 1);
  WVM8();
  BAR();

#pragma unroll 1
  for (int g = 0; g < NCH; ++g) {
    const bool st = (g + 1 < NCH);
    // P1: deferred A(buf1,kh1) for tile 2g+1 (issued by prev group's slot)
    rdB(0, 0); rdA(0, 0, 0);
    if (g > 0) stA(1, 1, 2 * g + 1);
    BAR(); WLG0();
    PRIO1(); mma(0); PRIO0();
    BAR();
    // P2
    rdA(0, 0, 1);
    if (st) stB(0, 0, 2 * g + 2);
    BAR(); WLG0();
    PRIO1(); mma(1); PRIO0();
    BAR();
    // P3
    rdB(0, 1); rdA(0, 1, 0);
    if (st) stA(0, 0, 2 * g + 2);
    BAR(); WLG0();
    PRIO1(); mma(0); PRIO0();
    BAR();
    // P4: buf1 (tile 2g+1) fully drained here
    rdA(0, 1, 1);
    if (st) { stB(0, 1, 2 * g + 2); WVM6(); } else { WVM0(); }
    BAR(); WLG0();
    PRIO1(); mma(1); PRIO0();
    BAR();
    // P5
    rdB(1, 0); rdA(1, 0, 0);
    if (st) stA(0, 1, 2 * g + 2);
    BAR(); WLG0();
    PRIO1(); mma(0); PRIO0();
    BAR();
    // P6
    rdA(1, 0, 1);
    if (st) stB(1, 0, 2 * g + 3);
    BAR(); WLG0();
    PRIO1(); mma(1); PRIO0();
    BAR();
    // P7
    rdB(1, 1); rdA(1, 1, 0);
    if (st) stA(1, 0, 2 * g + 3);
    BAR(); WLG0();
    PRIO1(); mma(0); PRIO0();
    BAR();
    // P8: buf0 (tile 2g+2) fully drained here
    rdA(1, 1, 1);
    if (st) { stB(1, 1, 2 * g + 3); WVM6(); }
    BAR(); WLG0();
    PRIO1(); mma(1); PRIO0();
    BAR();
  }

  // epilogue
  float bv[4] = {0.f, 0.f, 0.f, 0.f};
  const int c0 = n0 + wn * 64 + fr;
  if (bias) {
#pragma unroll
    for (int n = 0; n < 4; ++n) bv[n] = bias[c0 + n * 16];
  }
  float* Cz = C + (size_t)blockIdx.z * NR * NN;
  const int r0 = m0 + wm * 128 + kq * 4;
#pragma unroll
  for (int mi = 0; mi < 8; ++mi)
#pragma unroll
    for (int j = 0; j < 4; ++j) {
      float* p = Cz + (size_t)(r0 + mi * 16 + j) * NN + c0;
#pragma unroll
      for (int n = 0; n < 4; ++n)
        p[n * 16] = acc[mi][n][j] + bv[n];
    }
}

// ---------------------------------------------------------------- fused-path kernels (r4 fallback)

__global__ __launch_bounds__(256) void k_tanh_x(const float* __restrict__ x,
                                                bf16* __restrict__ xt) {
  const size_t i = ((size_t)blockIdx.x * 256 + threadIdx.x) * 4;
  const float4 v = *(const float4*)(x + i);
  bf16x4 r;
  r[0] = (bf16)tanhf(v.x);
  r[1] = (bf16)tanhf(v.y);
  r[2] = (bf16)tanhf(v.z);
  r[3] = (bf16)tanhf(v.w);
  *(bf16x4*)(xt + i) = r;
}

__global__ __launch_bounds__(256) void k_ln_tanh(const float* __restrict__ h,
                                                 const float* __restrict__ gamma,
                                                 const float* __restrict__ beta,
                                                 bf16* __restrict__ th) {
  const int n = blockIdx.x;
  const int t = threadIdx.x;
  const float* row = h + (size_t)n * DIM_H;

  float4 v[4];
  float s1 = 0.f, s2 = 0.f;
#pragma unroll
  for (int j = 0; j < 4; ++j) {
    v[j] = *(const float4*)(row + t * 16 + j * 4);
    s1 += v[j].x + v[j].y + v[j].z + v[j].w;
    s2 += v[j].x * v[j].x + v[j].y * v[j].y + v[j].z * v[j].z + v[j].w * v[j].w;
  }
#pragma unroll
  for (int off = 32; off >= 1; off >>= 1) {
    s1 += __shfl_xor(s1, off);
    s2 += __shfl_xor(s2, off);
  }
  __shared__ float red[8];
  if ((t & 63) == 0) { red[(t >> 6) * 2] = s1; red[(t >> 6) * 2 + 1] = s2; }
  __syncthreads();
  const float S1 = red[0] + red[2] + red[4] + red[6];
  const float S2 = red[1] + red[3] + red[5] + red[7];
  const float mu   = S1 * (1.f / DIM_H);
  const float var  = S2 * (1.f / DIM_H) - mu * mu;
  const float rstd = rsqrtf(var + 1e-5f);

  float tmp[16];
#pragma unroll
  for (int j = 0; j < 4; ++j) {
    const float4 g = *(const float4*)(gamma + t * 16 + j * 4);
    const float4 b = *(const float4*)(beta  + t * 16 + j * 4);
    tmp[j * 4 + 0] = tanhf((v[j].x - mu) * rstd * g.x + b.x);
    tmp[j * 4 + 1] = tanhf((v[j].y - mu) * rstd * g.y + b.y);
    tmp[j * 4 + 2] = tanhf((v[j].z - mu) * rstd * g.z + b.z);
    tmp[j * 4 + 3] = tanhf((v[j].w - mu) * rstd * g.w + b.w);
  }
  bf16x8 w0, w1;
#pragma unroll
  for (int j = 0; j < 8; ++j) { w0[j] = (bf16)tmp[j]; w1[j] = (bf16)tmp[8 + j]; }
  bf16* o = th + (size_t)n * DIM_H + t * 16;
  *(bf16x8*)o       = w0;
  *(bf16x8*)(o + 8) = w1;
}

template <int IND, int NZ>
__global__ __launch_bounds__(512, 2) void k_gemm8(const bf16* __restrict__ X,
                                                  const bf16* __restrict__ Bp,
                                                  float* __restrict__ C,
                                                  const float* __restrict__ bias,
                                                  const int NN) {
  constexpr int NCH = IND / 32 / NZ;
  constexpr int KTt = (IND / 32) * 2;

  __shared__ bf16 Ash[2][16384];
  __shared__ bf16 Bsh[2][16384];

  const int tid  = threadIdx.x;
  const int lane = tid & 63;
  const int wid  = tid >> 6;
  const int wm   = wid >> 2;
  const int wn   = wid & 3;
  const int fr   = lane & 15;
  const int kq   = lane >> 4;
  const int m0   = blockIdx.y * 256;
  const int n0   = blockIdx.x * 256;
  const int zc0  = blockIdx.z * NCH;

  const int ar = tid >> 1;
  const int aq = (tid & 1) * 2;

  f32x4 acc[8][4];
#pragma unroll
  for (int m = 0; m < 8; ++m)
#pragma unroll
    for (int n = 0; n < 4; ++n) acc[m][n] = (f32x4){0.f, 0.f, 0.f, 0.f};

  const bf16* xp = X + (size_t)(m0 + ar) * IND + (size_t)zc0 * 32 + aq * 8;
  const size_t bt0 = (size_t)blockIdx.x * KTt + (size_t)zc0 * 2;

  bf16x8 xn0, xn1;
  float  xf[16];
  bf16x8 afr[4], bfr[4];

  auto stB = [&](int d, int kh, int ktl) {
    const bf16* s = Bp + (bt0 + (size_t)ktl) * 16384 + kh * 8192 + tid * 8;
    bf16* l = &Bsh[d][kh * 8192 + tid * 8];
    gload_lds16(s, l);
    gload_lds16(s + 4096, l + 4096);
  };
  auto ldx = [&](int c) {
    const bf16* s = xp + (size_t)c * 32;
    xn0 = *(const bf16x8*)s;
    xn1 = *(const bf16x8*)(s + 8);
  };
  auto cvtxf = [&]() {
#pragma unroll
    for (int j = 0; j < 8; ++j) { xf[j] = (float)xn0[j]; xf[8 + j] = (float)xn1[j]; }
  };
  auto wA = [&](int d, int dh, bf16x8 w0, bf16x8 w1) {
    *(bf16x8*)&Ash[d][(dh * 4 + aq) * 2048 + ar * 8]       = w0;
    *(bf16x8*)&Ash[d][(dh * 4 + aq + 1) * 2048 + ar * 8]   = w1;
  };
  auto chebw = [&](int deg, bf16x8& w0, bf16x8& w1) {
#pragma unroll
    for (int j = 0; j < 8; ++j) {
      const float a = xf[j], b = xf[8 + j];
      const float a2 = a * a, b2 = b * b;
      float ra, rb;
      if (deg == 2)      { ra = 2.f * a2 - 1.f;            rb = 2.f * b2 - 1.f; }
      else if (deg == 3) { ra = a * (4.f * a2 - 3.f);      rb = b * (4.f * b2 - 3.f); }
      else               { ra = 8.f * a2 * (a2 - 1.f) + 1.f; rb = 8.f * b2 * (b2 - 1.f) + 1.f; }
      w0[j] = (bf16)ra; w1[j] = (bf16)rb;
    }
  };
  auto rdB = [&](int d, int kh) {
#pragma unroll
    for (int n = 0; n < 4; ++n)
      bfr[n] = *(const bf16x8*)&Bsh[d][(kh * 4 + kq) * 2048 + (wn * 64 + n * 16 + fr) * 8];
  };
  auto rdA = [&](int d, int kh, int mh) {
#pragma unroll
    for (int m = 0; m < 4; ++m)
      afr[m] = *(const bf16x8*)&Ash[d][(kh * 4 + kq) * 2048 + (wm * 128 + mh * 64 + m * 16 + fr) * 8];
  };
  auto mma = [&](int mh) {
#pragma unroll
    for (int m = 0; m < 4; ++m)
#pragma unroll
      for (int n = 0; n < 4; ++n)
        acc[mh * 4 + m][n] =
            __builtin_amdgcn_mfma_f32_16x16x32_bf16(afr[m], bfr[n], acc[mh * 4 + m][n], 0, 0, 0);
  };

  ldx(0);
  stB(0, 0, 0); stB(0, 1, 0);
  stB(1, 0, 1); stB(1, 1, 1);
  cvtxf();
  wA(0, 0, xn0, xn1);
  { bf16x8 w0, w1; chebw(2, w0, w1); wA(0, 1, w0, w1); }
  { bf16x8 w0, w1; chebw(3, w0, w1); wA(1, 0, w0, w1); }
  { bf16x8 w0, w1; chebw(4, w0, w1); wA(1, 1, w0, w1); }
  WVM0(); WLG0();
  BAR();

#pragma unroll 1
  for (int g = 0; g < NCH; ++g) {
    const bool st = (g + 1 < NCH);
    rdB(0, 0); rdA(0, 0, 0);
    if (g > 0) { bf16x8 w0, w1; chebw(4, w0, w1); wA(1, 1, w0, w1); }
    if (st) ldx(g + 1);
    BAR(); WLG0();
    PRIO1(); mma(0); PRIO0();
    BAR();
    rdA(0, 0, 1);
    if (st) stB(0, 0, 2 * (g + 1));
    BAR(); WLG0();
    PRIO1(); mma(1); PRIO0();
    BAR();
    rdB(0, 1); rdA(0, 1, 0);
    BAR(); WLG0();
    PRIO1(); mma(0); PRIO0();
    BAR();
    rdA(0, 1, 1);
    if (st) { stB(0, 1, 2 * (g + 1)); WVM6(); } else { WVM0(); }
    BAR(); WLG0();
    PRIO1(); mma(1); PRIO0();
    BAR();
    rdB(1, 0); rdA(1, 0, 0);
    if (st) { cvtxf(); wA(0, 0, xn0, xn1); }
    BAR(); WLG0();
    PRIO1(); mma(0); PRIO0();
    BAR();
    rdA(1, 0, 1);
    if (st) { bf16x8 w0, w1; chebw(2, w0, w1); wA(0, 1, w0, w1); }
    BAR(); WLG0();
    PRIO1(); mma(1); PRIO0();
    BAR();
    rdB(1, 1); rdA(1, 1, 0);
    if (st) { bf16x8 w0, w1; chebw(3, w0, w1); wA(1, 0, w0, w1); stB(1, 0, 2 * (g + 1) + 1); }
    BAR(); WLG0();
    PRIO1(); mma(0); PRIO0();
    BAR();
    rdA(1, 1, 1);
    if (st) { stB(1, 1, 2 * (g + 1) + 1); WVM4(); }
    BAR(); WLG0();
    PRIO1(); mma(1); PRIO0();
    BAR();
  }

  float bv[4] = {0.f, 0.f, 0.f, 0.f};
  const int c0 = n0 + wn * 64 + fr;
  if (bias) {
#pragma unroll
    for (int n = 0; n < 4; ++n) bv[n] = bias[c0 + n * 16];
  }
  float* Cz = C + (size_t)blockIdx.z * NR * NN;
  const int r0 = m0 + wm * 128 + kq * 4;
#pragma unroll
  for (int mi = 0; mi < 8; ++mi)
#pragma unroll
    for (int j = 0; j < 4; ++j) {
      float* p = Cz + (size_t)(r0 + mi * 16 + j) * NN + c0;
#pragma unroll
      for (int n = 0; n < 4; ++n)
        p[n * 16] = acc[mi][n][j] + bv[n];
    }
}

// out[row][c] = p0 + p1 + bias2[c]
__global__ __launch_bounds__(256) void k_reduce2(const float* __restrict__ p0,
                                                 const float* __restrict__ p1,
                                                 const float* __restrict__ bias,
                                                 float* __restrict__ out) {
  const size_t base = (size_t)blockIdx.x * 1024 + threadIdx.x * 4;
  const float4 a = *(const float4*)(p0 + base);
  const float4 b = *(const float4*)(p1 + base);
  const float4 c = *(const float4*)(bias + threadIdx.x * 4);
  float4 r;
  r.x = a.x + b.x + c.x;
  r.y = a.y + b.y + c.y;
  r.z = a.z + b.z + c.z;
  r.w = a.w + b.w + c.w;
  *(float4*)(out + base) = r;
}

// ---------------------------------------------------------------- launch

extern "C" void kernel_launch(void* const* d_in, const int* in_sizes, int n_in,
                              void* d_out, int out_size, void* d_ws, size_t ws_size,
                              hipStream_t stream) {
  const float* x         = (const float*)d_in[0];
  const float* coef_fc   = (const float*)d_in[1];
  const float* coef_proj = (const float*)d_in[2];
  const float* gamma     = (const float*)d_in[3];
  const float* beta      = (const float*)d_in[4];
  float* out = (float*)d_out;

  // shared layout
  char* w = (char*)d_ws;
  bf16*  B1p    = (bf16*)w;   w += (size_t)DIM_H * 4 * DIM_D * 2;   // 32 MB
  bf16*  B2p    = (bf16*)w;   w += (size_t)DIM_D * 4 * DIM_H * 2;   // 32 MB
  float* bias1  = (float*)w;  w += 16 * 1024;
  float* bias2  = (float*)w;  w += 16 * 1024;
  float* bpart1 = (float*)w;  w += (size_t)32 * DIM_H * 4;          // 512 KB
  float* bpart2 = (float*)w;  w += (size_t)128 * DIM_D * 4;         // 512 KB
  float* h      = (float*)w;  w += (size_t)NR * DIM_H * 4;          // 128 MB
  float* part   = h;                                                // overlays h
  char*  tail   = w;                                                // path-specific

  const size_t NEED_EXP = (size_t)(tail - (char*)d_ws) + (size_t)NR * DIM_H * 4 * 2; // +256MB Ax
  const bool EXP = (ws_size >= NEED_EXP);

  // shared prep: permuted B + bias
  k_prep_t<DIM_D, DIM_H><<<dim3(DIM_H / 256, DIM_D / 32), 256, 0, stream>>>(coef_fc, B1p, bpart1);
  k_prep_t<DIM_H, DIM_D><<<dim3(DIM_D / 256, DIM_H / 32), 256, 0, stream>>>(coef_proj, B2p, bpart2);
  k_bias_red<<<DIM_H / 256, 256, 0, stream>>>(bpart1, bias1, DIM_H, DIM_D / 32);
  k_bias_red<<<DIM_D / 256, 256, 0, stream>>>(bpart2, bias2, DIM_D, DIM_H / 32);

  if (EXP) {
    bf16* Ax = (bf16*)tail;   // 256 MB region; A1x (64 MB) then A2x (256 MB) overlaid
    k_tanh_cheb<<<NR * DIM_D / 2048, 256, 0, stream>>>(x, Ax);
    k_gemm8x<DIM_D, 1><<<dim3(DIM_H / 256, NR / 256, 1), 512, 0, stream>>>(
        Ax, B1p, h, bias1, DIM_H);
    k_lntanh_cheb<<<NR, 256, 0, stream>>>(h, gamma, beta, Ax);
    k_gemm8x<DIM_H, 2><<<dim3(DIM_D / 256, NR / 256, 2), 512, 0, stream>>>(
        Ax, B2p, part, nullptr, DIM_D);
  } else {
    bf16* xt = (bf16*)tail;
    bf16* th = xt + (size_t)NR * DIM_D;
    k_tanh_x<<<NR * DIM_D / 1024, 256, 0, stream>>>(x, xt);
    k_gemm8<DIM_D, 1><<<dim3(DIM_H / 256, NR / 256, 1), 512, 0, stream>>>(
        xt, B1p, h, bias1, DIM_H);
    k_ln_tanh<<<NR, 256, 0, stream>>>(h, gamma, beta, th);
    k_gemm8<DIM_H, 2><<<dim3(DIM_D / 256, NR / 256, 2), 512, 0, stream>>>(
        th, B2p, part, nullptr, DIM_D);
  }
  k_reduce2<<<NR, 256, 0, stream>>>(part, part + (size_t)NR * DIM_D, bias2, out);
}